// Round 7
// baseline (1364.797 us; speedup 1.0000x reference)
//
#include <hip/hip_runtime.h>
#include <hip/hip_bf16.h>
#include <cstdint>

#define D  512
#define D2 1024
#define BB 128
#define SS 128
#define NN 196
#define TT 12

typedef unsigned short u16;

__device__ __forceinline__ float bf2f(u16 h){
  union { unsigned int u; float f; } v; v.u = ((unsigned int)h) << 16; return v.f;
}

__device__ __forceinline__ float LDX(const void* p, size_t i, int isbf){
  if (isbf) return bf2f(((const u16*)p)[i]);
  return ((const float*)p)[i];
}

__device__ __forceinline__ float4 LD4(const void* p, size_t i, int isbf){
  if (isbf){
    ushort4 w = *(const ushort4*)((const u16*)p + i);
    return make_float4(bf2f(w.x), bf2f(w.y), bf2f(w.z), bf2f(w.w));
  }
  return *(const float4*)((const float*)p + i);
}

// ---------------- detect input dtype from ctx bit patterns ----------------
__global__ __launch_bounds__(256) void k_detect(const u16* ctx, int* flag){
  __shared__ int cnt;
  if (threadIdx.x == 0) cnt = 0;
  __syncthreads();
  int bad = 0;
  for (int i = threadIdx.x; i < 8192; i += 256){
    int e = (ctx[i] >> 7) & 0xFF;
    if (e == 0xFF || (e != 0 && (e < 90 || e > 160))) bad++;
  }
  atomicAdd(&cnt, bad);
  __syncthreads();
  if (threadIdx.x == 0) *flag = (cnt > 100) ? 0 : 1;   // 1 = bf16, 0 = fp32
}

// ---------------- prep1: transposes / scaled copies of weights ----------------
__global__ __launch_bounds__(256) void k_prep1(const void* q, const void* Wcq, const void* Wca,
      const void* Wwc, const void* Wrm, const void* Wrc, const void* Wra,
      float* qT, float* W1f, float* Wwcf, float* WrmTf, float* W2f, const int* flag){
  const int isbf = *flag;
  __shared__ float lds[32][33];
  int bk = blockIdx.x, tid = threadIdx.x;
  int tx = tid & 31, ty = tid >> 5;
  if (bk >= 1152){
    int l = bk - 1152;
    if (isbf){
      const u16* w = (const u16*)Wrc; const u16* s = (const u16*)Wra;
      for (int idx = l*256 + tid; idx < 524288; idx += 64*256)
        W2f[idx] = bf2f(w[idx]) * bf2f(s[idx >> 10]);
    } else {
      const float* w = (const float*)Wrc; const float* s = (const float*)Wra;
      for (int idx = l*256 + tid; idx < 524288; idx += 64*256)
        W2f[idx] = w[idx] * s[idx >> 10];
    }
    return;
  }
  const void* in = nullptr; const void* scale = nullptr; float* out = nullptr;
  int ld = 0, R = 0, tR = 0, tC = 0;
  if (bk < 128)      { in = q;   ld = 1024; R = 128; out = qT;    tR = bk & 3;  tC = bk >> 2; }
  else if (bk < 384) { int l = bk - 128; in = Wcq; ld = 1024; R = 512; out = W1f;  scale = Wca; tR = l & 15; tC = l >> 4; }
  else if (bk < 896) { int l = bk - 384; in = Wwc; ld = 1024; R = 512; out = Wwcf; tR = l & 15; tC = l >> 4; }
  else               { int l = bk - 896; in = Wrm; ld = 512;  R = 512; out = WrmTf;tR = l & 15; tC = l >> 4; }
  int r0 = tR*32, c0 = tC*32;
  #pragma unroll
  for (int kk = 0; kk < 4; kk++){
    int r = r0 + ty + kk*8;
    float v = LDX(in, (size_t)r*ld + c0 + tx, isbf);
    if (scale) v *= LDX(scale, r, isbf);
    lds[tx][ty + kk*8] = v;
  }
  __syncthreads();
  #pragma unroll
  for (int kk = 0; kk < 4; kk++){
    int oc = ty + kk*8;
    out[(size_t)(c0 + oc)*R + r0 + tx] = lds[oc][tx];
  }
}

// ---------------- K_P: 384 blocks (12t x 32et), 512 thr, e-tile 16 ----------------
__global__ __launch_bounds__(512) void k_P(const float* qT, const void* Wp, const void* bp,
                                           float* P, const int* flag){
  const int isbf = *flag;
  int bk = blockIdx.x;
  int t = bk >> 5, et = bk & 31;
  int tid = threadIdx.x;
  int b = tid & 127;
  int ih = __builtin_amdgcn_readfirstlane(tid >> 7);   // 0..3
  int e0 = et*16 + ih*4;
  float acc[4];
  #pragma unroll
  for (int kk = 0; kk < 4; kk++) acc[kk] = LDX(bp, t*D + e0 + kk, isbf);
  size_t wo = (size_t)(t*D + e0)*D2;
  if (isbf){
    const u16* wb = (const u16*)Wp + wo;
    for (int x = 0; x < D2; x += 8){
      float a[8];
      #pragma unroll
      for (int u = 0; u < 8; u++) a[u] = qT[(x+u)*BB + b];
      #pragma unroll
      for (int kk = 0; kk < 4; kk++){
        ushort4 w0 = *(const ushort4*)(wb + kk*D2 + x);
        ushort4 w1 = *(const ushort4*)(wb + kk*D2 + x + 4);
        acc[kk] += a[0]*bf2f(w0.x) + a[1]*bf2f(w0.y) + a[2]*bf2f(w0.z) + a[3]*bf2f(w0.w)
                 + a[4]*bf2f(w1.x) + a[5]*bf2f(w1.y) + a[6]*bf2f(w1.z) + a[7]*bf2f(w1.w);
      }
    }
  } else {
    const float* wb = (const float*)Wp + wo;
    for (int x = 0; x < D2; x += 8){
      float a[8];
      #pragma unroll
      for (int u = 0; u < 8; u++) a[u] = qT[(x+u)*BB + b];
      #pragma unroll
      for (int kk = 0; kk < 4; kk++){
        float4 w0 = *(const float4*)(wb + kk*D2 + x);
        float4 w1 = *(const float4*)(wb + kk*D2 + x + 4);
        acc[kk] += a[0]*w0.x + a[1]*w0.y + a[2]*w0.z + a[3]*w0.w
                 + a[4]*w1.x + a[5]*w1.y + a[6]*w1.z + a[7]*w1.w;
      }
    }
  }
  #pragma unroll
  for (int kk = 0; kk < 4; kk++) P[(size_t)(t*D + e0 + kk)*BB + b] = acc[kk];
}

// ---------------- K_pp2: 384 blocks (12t x 32jt), 512 thr, j-tile 16 ----------------
__global__ __launch_bounds__(512) void k_pp2(const float* P, const void* Wcq, const void* bcq,
                                             const void* Wca, float* pp2, const int* flag){
  const int isbf = *flag;
  int bk = blockIdx.x;
  int t = bk >> 5, jt = bk & 31;
  int tid = threadIdx.x;
  int b = tid & 127;
  int ih = __builtin_amdgcn_readfirstlane(tid >> 7);
  int j0 = jt*16 + ih*4;
  float acc[4];
  #pragma unroll
  for (int kk = 0; kk < 4; kk++) acc[kk] = LDX(bcq, j0 + kk, isbf);
  if (isbf){
    const u16* w = (const u16*)Wcq;
    for (int e = 0; e < D; e += 8){
      float a[8];
      #pragma unroll
      for (int u = 0; u < 8; u++) a[u] = P[(size_t)(t*D + e + u)*BB + b];
      #pragma unroll
      for (int kk = 0; kk < 4; kk++){
        ushort4 w0 = *(const ushort4*)(w + (size_t)(j0+kk)*D2 + D + e);
        ushort4 w1 = *(const ushort4*)(w + (size_t)(j0+kk)*D2 + D + e + 4);
        acc[kk] += a[0]*bf2f(w0.x) + a[1]*bf2f(w0.y) + a[2]*bf2f(w0.z) + a[3]*bf2f(w0.w)
                 + a[4]*bf2f(w1.x) + a[5]*bf2f(w1.y) + a[6]*bf2f(w1.z) + a[7]*bf2f(w1.w);
      }
    }
  } else {
    const float* w = (const float*)Wcq;
    for (int e = 0; e < D; e += 8){
      float a[8];
      #pragma unroll
      for (int u = 0; u < 8; u++) a[u] = P[(size_t)(t*D + e + u)*BB + b];
      #pragma unroll
      for (int kk = 0; kk < 4; kk++){
        float4 w0 = *(const float4*)(w + (size_t)(j0+kk)*D2 + D + e);
        float4 w1 = *(const float4*)(w + (size_t)(j0+kk)*D2 + D + e + 4);
        acc[kk] += a[0]*w0.x + a[1]*w0.y + a[2]*w0.z + a[3]*w0.w
                 + a[4]*w1.x + a[5]*w1.y + a[6]*w1.z + a[7]*w1.w;
      }
    }
  }
  #pragma unroll
  for (int kk = 0; kk < 4; kk++)
    pp2[(size_t)(t*D + j0 + kk)*BB + b] = acc[kk] * LDX(Wca, j0 + kk, isbf);
}

// ---------------- K_initA: b-independent base vectors via K-split reduction ----------------
__global__ __launch_bounds__(256) void k_initA(const void* ctrl0, const void* mem0,
                                               const void* Wcq, const void* Wca,
                                               const void* Wrm, const void* brm,
                                               float* ubase, float* mmb, const int* flag){
  const int isbf = *flag;
  int bk = blockIdx.x, tid = threadIdx.x;
  int lane = tid & 63, w = tid >> 6;
  int grp = lane >> 3, k = lane & 7;
  int isU = (bk < 16);
  int o = (isU ? bk : bk - 16)*32 + w*8 + grp;
  const void* vec = isU ? ctrl0 : mem0;
  const void* mat = isU ? Wcq : Wrm;
  int ld = isU ? D2 : D;
  float acc = 0.f;
  #pragma unroll 4
  for (int it = 0; it < 16; it++){
    int d = it*32 + k*4;
    float4 v = LD4(vec, d, isbf);
    float4 m = LD4(mat, (size_t)o*ld + d, isbf);
    acc += v.x*m.x + v.y*m.y + v.z*m.z + v.w*m.w;
  }
  acc += __shfl_xor(acc, 1, 64);
  acc += __shfl_xor(acc, 2, 64);
  acc += __shfl_xor(acc, 4, 64);
  if (k == 0){
    if (isU) ubase[o] = acc * LDX(Wca, o, isbf);
    else     mmb[o]   = acc + LDX(brm, o, isbf);
  }
}

// ---------------- K_initB: broadcast u0, mm0, m_{-1}, zero wbuf ----------------
__global__ __launch_bounds__(256) void k_initB(const float* ubase, const float* mmb,
                                               const void* mem0, const float* pp2,
                                               float* u0, float* mm0, float* act0, float* wbuf,
                                               const int* flag){
  const int isbf = *flag;
  for (int idx = blockIdx.x*256 + threadIdx.x; idx < 3*D*BB + D2*BB; idx += 160*256){
    if (idx < D*BB)            u0[idx] = ubase[idx >> 7] + pp2[idx];
    else if (idx < 2*D*BB)   { int x = idx - D*BB;   mm0[x] = mmb[x >> 7]; }
    else if (idx < 3*D*BB)   { int x = idx - 2*D*BB; act0[D*BB + x] = LDX(mem0, x >> 7, isbf); }
    else                       wbuf[idx - 3*D*BB] = 0.f;
  }
}

// ---------------- K_A1: single-pass online-softmax ctx attention + mm gemv ----------------
// bk<128: attention for b=bk; bk>=128 (t>=1): mm_t += Wrm*m_{t-1}
__global__ __launch_bounds__(512) void k_A1(const void* ctx, const float* ubuf, float* cbuf,
                                            const float* act_cur, float* mm_cur,
                                            const float* WrmTf, int t, const int* flag){
  int bk = blockIdx.x, tid = threadIdx.x;
  if (bk >= BB){
    if (t == 0) return;
    int l = bk - BB;                       // 0..63
    int b = tid & 127;
    int ih = (tid >> 7) & 3;
    int it = l >> 2, kc = l & 3;
    int i0 = it*32 + ih*8;
    float acc[8] = {0.f,0.f,0.f,0.f,0.f,0.f,0.f,0.f};
    int d0 = kc*128;
    for (int d = d0; d < d0 + 128; d += 8){
      float av[8];
      #pragma unroll
      for (int u = 0; u < 8; u++) av[u] = act_cur[(size_t)(D + d + u)*BB + b];
      #pragma unroll
      for (int u = 0; u < 8; u++){
        float4 w0 = *(const float4*)(WrmTf + (size_t)(d+u)*D + i0);
        float4 w1 = *(const float4*)(WrmTf + (size_t)(d+u)*D + i0 + 4);
        acc[0]+=av[u]*w0.x; acc[1]+=av[u]*w0.y; acc[2]+=av[u]*w0.z; acc[3]+=av[u]*w0.w;
        acc[4]+=av[u]*w1.x; acc[5]+=av[u]*w1.y; acc[6]+=av[u]*w1.z; acc[7]+=av[u]*w1.w;
      }
    }
    #pragma unroll
    for (int kk = 0; kk < 8; kk++) atomicAdd(&mm_cur[(size_t)(i0 + kk)*BB + b], acc[kk]);
    return;
  }
  const int isbf = *flag;
  __shared__ float cch[16][D];     // 32 KB chunk cache
  __shared__ float lg[16];
  int b = bk;
  int lane = tid & 63, wv = tid >> 6;          // 8 waves
  // ur matches load pattern: d = lane*4+kk (kk<4), d = 256+lane*4+(kk-4) (kk>=4)
  float ur[8];
  #pragma unroll
  for (int kk = 0; kk < 4; kk++) ur[kk]   = ubuf[(lane*4 + kk)*BB + b];
  #pragma unroll
  for (int kk = 0; kk < 4; kk++) ur[4+kk] = ubuf[(256 + lane*4 + kk)*BB + b];
  float m = -INFINITY, lsum = 0.f, o = 0.f;    // thread owns d = tid
  for (int c = 0; c < 8; c++){
    int s0 = c*16;
    // logit phase: each wave handles rows s0+wv and s0+8+wv, stashing rows in LDS
    #pragma unroll
    for (int rr = 0; rr < 2; rr++){
      int s = s0 + rr*8 + wv;
      float4 c0, c1;
      if (isbf){
        const u16* crow = (const u16*)ctx + ((size_t)(b*SS + s))*D;
        ushort4 h0 = *(const ushort4*)(crow + lane*4);
        ushort4 h1 = *(const ushort4*)(crow + 256 + lane*4);
        c0 = make_float4(bf2f(h0.x), bf2f(h0.y), bf2f(h0.z), bf2f(h0.w));
        c1 = make_float4(bf2f(h1.x), bf2f(h1.y), bf2f(h1.z), bf2f(h1.w));
      } else {
        const float* crow = (const float*)ctx + ((size_t)(b*SS + s))*D;
        c0 = *(const float4*)(crow + lane*4);
        c1 = *(const float4*)(crow + 256 + lane*4);
      }
      *(float4*)&cch[s - s0][lane*4]       = c0;
      *(float4*)&cch[s - s0][256 + lane*4] = c1;
      float dot = ur[0]*c0.x + ur[1]*c0.y + ur[2]*c0.z + ur[3]*c0.w
                + ur[4]*c1.x + ur[5]*c1.y + ur[6]*c1.z + ur[7]*c1.w;
      #pragma unroll
      for (int off = 32; off; off >>= 1) dot += __shfl_down(dot, off, 64);
      if (lane == 0) lg[s - s0] = dot;
    }
    __syncthreads();
    // online update: all 512 threads, thread owns d = tid
    float Mc = lg[0];
    #pragma unroll
    for (int s = 1; s < 16; s++) Mc = fmaxf(Mc, lg[s]);
    float mn = fmaxf(m, Mc);
    float sc = __expf(m - mn);
    lsum *= sc; o *= sc;
    #pragma unroll
    for (int s = 0; s < 16; s++){
      float e = __expf(lg[s] - mn);
      lsum += e;
      o += e * cch[s][tid];
    }
    m = mn;
    __syncthreads();
  }
  cbuf[tid*BB + b] = o / lsum;
}

// ---------------- K_G2: w += c@W2f (atomic, K-split x4) + preload next-step accumulators ----------------
__global__ __launch_bounds__(256) void k_G2(const float* cbuf, const float* W2f, float* wbuf,
                                            const float* pp2_next, float* u_nxt,
                                            const void* brm, float* mm_nxt,
                                            const void* bwc, float* act_nxt, int t, const int* flag){
  int bk = blockIdx.x, tid = threadIdx.x;
  if (bk < 512){
    int et = bk >> 2, kc = bk & 3;
    int b = tid & 127;
    int ih = __builtin_amdgcn_readfirstlane(tid >> 7);
    int e0 = et*8 + ih*4;
    float acc[4] = {0.f, 0.f, 0.f, 0.f};
    int j0 = kc*128;
    for (int j = j0; j < j0 + 128; j += 8){
      float av[8];
      #pragma unroll
      for (int u = 0; u < 8; u++) av[u] = cbuf[(j+u)*BB + b];
      #pragma unroll
      for (int u = 0; u < 8; u++){
        float4 wv = *(const float4*)(W2f + (size_t)(j+u)*D2 + e0);
        acc[0] += av[u]*wv.x; acc[1] += av[u]*wv.y;
        acc[2] += av[u]*wv.z; acc[3] += av[u]*wv.w;
      }
    }
    #pragma unroll
    for (int kk = 0; kk < 4; kk++) atomicAdd(&wbuf[(e0+kk)*BB + b], acc[kk]);
  } else if (bk < 528){
    if (t < TT-1)
      for (int x = (bk-512)*256 + tid; x < D*BB; x += 16*256) u_nxt[x] = pp2_next[x];
  } else if (bk < 544){
    if (t < TT-1){
      const int isbf = *flag;
      for (int x = (bk-528)*256 + tid; x < D*BB; x += 16*256)
        mm_nxt[x] = LDX(brm, x >> 7, isbf);
    }
  } else {
    const int isbf = *flag;
    if (isbf){
      const u16* w = (const u16*)bwc;
      for (int x = (bk-544)*256 + tid; x < D*BB; x += 16*256) act_nxt[D*BB + x] = bf2f(w[x >> 7]);
    } else {
      const float* w = (const float*)bwc;
      for (int x = (bk-544)*256 + tid; x < D*BB; x += 16*256) act_nxt[D*BB + x] = w[x >> 7];
    }
  }
}

// ---------------- K_A2: k attention (per-batch block, 512 thr) -> r into act_cur ----------------
__global__ __launch_bounds__(512) void k_A2(const void* kmat, const float* wbuf,
                                            const float* mmbuf, float* act_cur, const int* flag){
  const int isbf = *flag;
  int b = blockIdx.x, tid = threadIdx.x;
  __shared__ float u2[D];
  __shared__ float lg[256];
  __shared__ float red[256];
  __shared__ float ps[2][256];
  u2[tid] = wbuf[tid*BB + b]*mmbuf[tid*BB + b] + wbuf[(D + tid)*BB + b];
  __syncthreads();
  {
    int half = tid >> 8;
    int n = tid & 255;
    float part = 0.f;
    if (n < NN){
      float c[8];
      #pragma unroll
      for (int u = 0; u < 8; u++) c[u] = 0.f;
      int d0 = half*256;
      if (isbf){
        const u16* kb = (const u16*)kmat + (size_t)b*D*NN + n;
        for (int dd = 0; dd < 256; dd += 8){
          #pragma unroll
          for (int u = 0; u < 8; u++) c[u] += u2[d0+dd+u]*bf2f(kb[(size_t)(d0+dd+u)*NN]);
        }
      } else {
        const float* kb = (const float*)kmat + (size_t)b*D*NN + n;
        for (int dd = 0; dd < 256; dd += 8){
          #pragma unroll
          for (int u = 0; u < 8; u++) c[u] += u2[d0+dd+u]*kb[(size_t)(d0+dd+u)*NN];
        }
      }
      part = (((c[0]+c[1]) + (c[2]+c[3])) + ((c[4]+c[5]) + (c[6]+c[7])));
    }
    ps[half][n] = part;
  }
  __syncthreads();
  if (tid < 256){
    float logit = (tid < NN) ? (ps[0][tid] + ps[1][tid]) : -INFINITY;
    lg[tid] = logit; red[tid] = logit;
  }
  __syncthreads();
  for (int off = 128; off; off >>= 1){ if (tid < off) red[tid] = fmaxf(red[tid], red[tid+off]); __syncthreads(); }
  float M = red[0];
  __syncthreads();
  if (tid < 256){ float e = (tid < NN) ? __expf(lg[tid] - M) : 0.f; lg[tid] = e; red[tid] = e; }
  __syncthreads();
  for (int off = 128; off; off >>= 1){ if (tid < off) red[tid] += red[tid+off]; __syncthreads(); }
  float inv = 1.f / red[0];
  int lane = tid & 63, wv = tid >> 6;
  for (int i = 0; i < 32; i++){
    int dA = wv + i*16, dB = dA + 8;
    float p, qv;
    if (isbf){
      const u16* krA = (const u16*)kmat + (size_t)b*D*NN + (size_t)dA*NN;
      const u16* krB = (const u16*)kmat + (size_t)b*D*NN + (size_t)dB*NN;
      p  = lg[lane]*bf2f(krA[lane]) + lg[lane+64]*bf2f(krA[lane+64]) + lg[lane+128]*bf2f(krA[lane+128]);
      qv = lg[lane]*bf2f(krB[lane]) + lg[lane+64]*bf2f(krB[lane+64]) + lg[lane+128]*bf2f(krB[lane+128]);
      if (lane < NN - 192){
        p  += lg[lane+192]*bf2f(krA[lane+192]);
        qv += lg[lane+192]*bf2f(krB[lane+192]);
      }
    } else {
      const float* krA = (const float*)kmat + (size_t)b*D*NN + (size_t)dA*NN;
      const float* krB = (const float*)kmat + (size_t)b*D*NN + (size_t)dB*NN;
      p  = lg[lane]*krA[lane] + lg[lane+64]*krA[lane+64] + lg[lane+128]*krA[lane+128];
      qv = lg[lane]*krB[lane] + lg[lane+64]*krB[lane+64] + lg[lane+128]*krB[lane+128];
      if (lane < NN - 192){
        p  += lg[lane+192]*krA[lane+192];
        qv += lg[lane+192]*krB[lane+192];
      }
    }
    #pragma unroll
    for (int off = 32; off; off >>= 1){
      p  += __shfl_down(p , off, 64);
      qv += __shfl_down(qv, off, 64);
    }
    if (lane == 0){
      act_cur[dA*BB + b] = p  * inv;
      act_cur[dB*BB + b] = qv * inv;
    }
  }
}

// ---------------- K_G3: m, u_next (atomic K-split gemvs) + zero wbuf for next step ----------------
__global__ __launch_bounds__(256) void k_G3(const float* act_cur, const float* cbuf,
                                            const float* Wwcf, const float* W1f,
                                            float* act_nxt, float* u_nxt, float* wbuf,
                                            int t){
  int bk = blockIdx.x, tid = threadIdx.x;
  int b = tid & 127;
  int ih = __builtin_amdgcn_readfirstlane(tid >> 7);
  if (bk < 256){
    int it = bk >> 3, kc = bk & 7;
    int i0 = it*16 + ih*8;
    float acc[8] = {0.f,0.f,0.f,0.f,0.f,0.f,0.f,0.f};
    int e0 = kc*128;
    for (int e = e0; e < e0 + 128; e += 8){
      float av[8];
      #pragma unroll
      for (int u = 0; u < 8; u++) av[u] = act_cur[(e+u)*BB + b];
      #pragma unroll
      for (int u = 0; u < 8; u++){
        float4 w0 = *(const float4*)(Wwcf + (size_t)(e+u)*D + i0);
        float4 w1 = *(const float4*)(Wwcf + (size_t)(e+u)*D + i0 + 4);
        acc[0]+=av[u]*w0.x; acc[1]+=av[u]*w0.y; acc[2]+=av[u]*w0.z; acc[3]+=av[u]*w0.w;
        acc[4]+=av[u]*w1.x; acc[5]+=av[u]*w1.y; acc[6]+=av[u]*w1.z; acc[7]+=av[u]*w1.w;
      }
    }
    #pragma unroll
    for (int kk = 0; kk < 8; kk++) atomicAdd(&act_nxt[(size_t)(D + i0 + kk)*BB + b], acc[kk]);
  } else if (bk < 384){
    if (t == TT-1) return;
    int l = bk - 256;
    int it = l >> 2, kc = l & 3;
    int j0 = it*16 + ih*8;
    float acc[8] = {0.f,0.f,0.f,0.f,0.f,0.f,0.f,0.f};
    int e0 = kc*128;
    for (int e = e0; e < e0 + 128; e += 8){
      float av[8];
      #pragma unroll
      for (int u = 0; u < 8; u++) av[u] = cbuf[(e+u)*BB + b];
      #pragma unroll
      for (int u = 0; u < 8; u++){
        float4 w0 = *(const float4*)(W1f + (size_t)(e+u)*D + j0);
        float4 w1 = *(const float4*)(W1f + (size_t)(e+u)*D + j0 + 4);
        acc[0]+=av[u]*w0.x; acc[1]+=av[u]*w0.y; acc[2]+=av[u]*w0.z; acc[3]+=av[u]*w0.w;
        acc[4]+=av[u]*w1.x; acc[5]+=av[u]*w1.y; acc[6]+=av[u]*w1.z; acc[7]+=av[u]*w1.w;
      }
    }
    #pragma unroll
    for (int kk = 0; kk < 8; kk++) atomicAdd(&u_nxt[(j0 + kk)*BB + b], acc[kk]);
  } else {
    if (t == TT-1) return;
    for (int x = (bk-384)*256 + tid; x < D2*BB; x += 16*256) wbuf[x] = 0.f;
  }
}

// ---------------- K_out: m[i,b] fp32 -> out[b,i] (bf16 or f32) ----------------
__global__ __launch_bounds__(256) void k_out(const float* act_fin, void* out, const int* flag){
  const int isbf = *flag;
  __shared__ float lds[32][33];
  int bk = blockIdx.x;
  int it = bk >> 2, bt = bk & 3;
  int tx = threadIdx.x & 31, ty = threadIdx.x >> 5;
  #pragma unroll
  for (int kk = 0; kk < 4; kk++){
    int i = it*32 + ty + kk*8;
    lds[tx][ty + kk*8] = act_fin[(D + i)*BB + bt*32 + tx];
  }
  __syncthreads();
  if (isbf){
    __hip_bfloat16* o = (__hip_bfloat16*)out;
    #pragma unroll
    for (int kk = 0; kk < 4; kk++){
      int bb = bt*32 + ty + kk*8;
      o[(size_t)bb*D + it*32 + tx] = __float2bfloat16(lds[ty + kk*8][tx]);
    }
  } else {
    float* o = (float*)out;
    #pragma unroll
    for (int kk = 0; kk < 4; kk++){
      int bb = bt*32 + ty + kk*8;
      o[(size_t)bb*D + it*32 + tx] = lds[ty + kk*8][tx];
    }
  }
}

extern "C" void kernel_launch(void* const* d_in, const int* in_sizes, int n_in,
                              void* d_out, int out_size, void* d_ws, size_t ws_size,
                              hipStream_t stream){
  const void* ctx  = d_in[0];
  const void* q    = d_in[1];
  const void* kmat = d_in[2];
  const void* mem0 = d_in[3];
  const void* ctrl0= d_in[4];
  const void* Wp   = d_in[5];
  const void* bp   = d_in[6];
  const void* Wcq  = d_in[7];
  const void* bcq  = d_in[8];
  const void* Wca  = d_in[9];
  const void* Wrm  = d_in[11];
  const void* brm  = d_in[12];
  const void* Wrc  = d_in[13];
  const void* Wra  = d_in[15];
  const void* Wwc  = d_in[17];
  const void* bwc  = d_in[18];

  float* W      = (float*)d_ws;
  float* qT     = W;
  float* P      = W + 131072;
  float* pp2    = W + 917504;
  float* W1f    = W + 1703936;
  float* W2f    = W + 1966080;
  float* Wwcf   = W + 2490368;
  float* WrmTf  = W + 3014656;
  float* ubuf   = W + 3801600;   // 2 x 65536
  float* cbuf   = W + 3932672;
  float* wbuf   = W + 3998208;
  float* mmbuf  = W + 4129280;   // 2 x 65536
  float* actb   = W + 4260352;   // 2 x 131072
  int*   flag   = (int*)(W + 4522496);
  float* ubase  = W + 4522560;   // 512
  float* mmb    = W + 4523072;   // 512

  hipLaunchKernelGGL(k_detect, dim3(1), dim3(256), 0, stream, (const u16*)ctx, flag);
  hipLaunchKernelGGL(k_prep1, dim3(1216), dim3(256), 0, stream,
                     q, Wcq, Wca, Wwc, Wrm, Wrc, Wra, qT, W1f, Wwcf, WrmTf, W2f, flag);
  hipLaunchKernelGGL(k_P,    dim3(384), dim3(512), 0, stream, qT, Wp, bp, P, flag);
  hipLaunchKernelGGL(k_pp2,  dim3(384), dim3(512), 0, stream, P, Wcq, bcq, Wca, pp2, flag);
  hipLaunchKernelGGL(k_initA, dim3(32), dim3(256), 0, stream,
                     ctrl0, mem0, Wcq, Wca, Wrm, brm, ubase, mmb, flag);
  hipLaunchKernelGGL(k_initB, dim3(160), dim3(256), 0, stream,
                     ubase, mmb, mem0, pp2, ubuf, mmbuf, actb, wbuf, flag);

  for (int t = 0; t < TT; t++){
    int cur = t & 1, nxt = 1 - cur;
    hipLaunchKernelGGL(k_A1, dim3(192), dim3(512), 0, stream,
                       ctx, ubuf + cur*65536, cbuf,
                       actb + cur*131072, mmbuf + cur*65536, WrmTf, t, flag);
    hipLaunchKernelGGL(k_G2, dim3(560), dim3(256), 0, stream,
                       cbuf, W2f, wbuf,
                       pp2 + ((t+1 < TT) ? (t+1)*65536 : 0), ubuf + nxt*65536,
                       brm, mmbuf + nxt*65536,
                       bwc, actb + nxt*131072, t, flag);
    hipLaunchKernelGGL(k_A2, dim3(128), dim3(512), 0, stream,
                       kmat, wbuf, mmbuf + cur*65536, actb + cur*131072, flag);
    hipLaunchKernelGGL(k_G3, dim3(400), dim3(256), 0, stream,
                       actb + cur*131072, cbuf, Wwcf, W1f,
                       actb + nxt*131072, ubuf + nxt*65536, wbuf, t);
  }
  hipLaunchKernelGGL(k_out, dim3(64), dim3(256), 0, stream, actb, d_out, flag);
}